// Round 4
// baseline (311.025 us; speedup 1.0000x reference)
//
#include <hip/hip_runtime.h>
#include <hip/hip_bf16.h>

using u16 = unsigned short;
using u32 = unsigned int;

typedef __attribute__((ext_vector_type(8))) short bf16x8;
typedef __attribute__((ext_vector_type(4))) float f32x4;
typedef __attribute__((ext_vector_type(2))) float f32x2;
typedef __attribute__((ext_vector_type(4))) u32 u32x4;

#define MFMA16(a, b, c) __builtin_amdgcn_mfma_f32_16x16x32_bf16((a), (b), (c), 0, 0, 0)

union FragU { u32 u[4]; bf16x8 v; u32x4 q; };

__device__ __forceinline__ bf16x8 mk_frag(u32 a, u32 b, u32 c, u32 d) {
  FragU f; f.u[0] = a; f.u[1] = b; f.u[2] = c; f.u[3] = d; return f.v;
}
__device__ __forceinline__ bf16x8 as_frag(u32x4 x) { FragU f; f.q = x; return f.v; }

__device__ __forceinline__ u16 f2bf(float x) {
  __hip_bfloat16 h = __float2bfloat16(x);
  u16 r; __builtin_memcpy(&r, &h, 2); return r;
}

__device__ __forceinline__ u32 pk_bf16(float a, float b) {
  __hip_bfloat162 h = __float22bfloat162_rn(make_float2(a, b));
  u32 r; __builtin_memcpy(&r, &h, 4); return r;
}

__device__ __forceinline__ float fast_tanh(float x) {
  // tanh(x) = 1 - 2/(1 + exp2(x * 2*log2(e)))
  float t = __builtin_amdgcn_exp2f(x * 2.885390081777927f);
  return __builtin_fmaf(-2.0f, __builtin_amdgcn_rcpf(1.0f + t), 1.0f);
}

// Flipped orientation: every layer computes D[hidden][point] with A = W^T, B = activations.
// With contraction order K(ks,8q+j) = 32ks + 16*(j>>2) + 4q + (j&3), the next layer's
// B-fragment is exactly the lane's OWN packed tanh outputs of D-tiles 2ks, 2ks+1:
// activations never leave registers (no LDS hbuf, no shuffles, no repacks).
//
// Register discipline (rounds 1-3, measured on this toolchain):
//  - __launch_bounds__ 2nd arg acts as BLOCKS/CU and the occupancy target is quantized to
//    power-of-2 waves/SIMD: (512,4)->cap 64, (512,2)->cap 128, (384,2)->STILL cap 128.
//    There is no 168-VGPR rung. The cap is 128; the live set must fit it.
//  - The u/v two-tile scheme (64 activation words live) spilled ~500 MB to scratch at
//    cap 128 (FETCH_SIZE blowup, 2.3 TB/s scratch traffic). Fix: ONE 16-point tile per
//    iteration -> peak live ~60 VGPRs, ~60 regs of scheduler slack. LDS read cost per
//    point doubles (each weight ds_read feeds 1 MFMA) but stays ~20 us/CU on the LDS
//    pipe vs the ~31 us VALU floor - hidden at 4 waves/SIMD.

#define LDS_W2 0          // 32768 B
#define LDS_W3 32768      // 32768 B
#define LDS_W4 65536      //   512 B (2 rows x 256)
#define LDS_B2 66048      //   512 B f32[128]
#define LDS_B3 66560      //   512 B f32[128]
#define LDS_W1 67072      //  2048 B (128 rows x 16 B, q==0 A-chunk incl. bias at j=4)
#define LDS_TOTAL 69120   // 2 WGs/CU co-resident (138240 <= 163840)

__global__ void __launch_bounds__(512, 2) mlp_fused(
    const float* __restrict__ Xg, const float* __restrict__ Yg,
    const float* __restrict__ C1g, const float* __restrict__ C2g,
    const float* __restrict__ W1g, const float* __restrict__ B1g,
    const float* __restrict__ W2g, const float* __restrict__ B2g,
    const float* __restrict__ W3g, const float* __restrict__ B3g,
    const float* __restrict__ W4g, const float* __restrict__ B4g,
    float* __restrict__ Og, int npts, int nwaves_total)
{
  extern __shared__ char lds[];
  const int tid = threadIdx.x;

  // ---- stage W2^T / W3^T as K-interleaved, bank-swizzled A-fragments ----
  for (int i = tid; i < 16384; i += 512) {
    int k = i >> 7, n = i & 127;                       // W[k][n], k = hid_in, n = hid_out
    int kc = ((k >> 5) << 2) | ((k >> 2) & 3);         // chunk = 4*ks + q
    int j  = (k & 3) | (((k >> 4) & 1) << 2);          // slot within chunk
    int off = n * 256 + ((kc ^ (n & 15)) << 4) + (j << 1);
    *(u16*)(lds + LDS_W2 + off) = f2bf(W2g[i]);
    *(u16*)(lds + LDS_W3 + off) = f2bf(W3g[i]);
  }
  if (tid < 256) {                                     // W4 is [128][2] row-major
    int k = tid >> 1, o = tid & 1;
    int kc = ((k >> 5) << 2) | ((k >> 2) & 3);
    int j  = (k & 3) | (((k >> 4) & 1) << 2);
    *(u16*)(lds + LDS_W4 + o * 256 + (kc << 4) + (j << 1)) = f2bf(W4g[tid]);
  }
  if (tid < 128) {
    ((float*)(lds + LDS_B2))[tid] = B2g[tid];
    ((float*)(lds + LDS_B3))[tid] = B3g[tid];
    // W1 augmented A-chunk (q==0 only): j=0..3 -> W1[0..3][n], j=4 -> b1[n]
    u32* w1r = (u32*)(lds + LDS_W1 + tid * 16);
    w1r[0] = pk_bf16(W1g[tid],       W1g[128 + tid]);
    w1r[1] = pk_bf16(W1g[256 + tid], W1g[384 + tid]);
    w1r[2] = pk_bf16(B1g[tid], 0.f);
    w1r[3] = 0u;
  }
  __syncthreads();

  const int wave = tid >> 6;
  const int lane = tid & 63;
  const int q = lane >> 4;
  const int c = lane & 15;
  const int wgid = blockIdx.x * 8 + wave;

  int posA[4];
#pragma unroll
  for (int ks = 0; ks < 4; ks++) posA[ks] = c * 256 + (((ks * 4 + q) ^ c) << 4);
  const int biasaddr = q * 16;
  const int w4addr = (c & 1) * 256 + q * 16;   // c>=2 lanes duplicate rows -> unused D rows
  const float b4_0 = B4g[0], b4_1 = B4g[1];

  const int nbatch = npts >> 4;   // ONE 16-point tile per wave-iteration

  // software-pipelined input fetch (q==0 lanes only; packed at arrival: 2 live u32)
  u32 b1u0 = 0, b1u1 = 0;
  const u32 b1w2 = (q == 0) ? 0x00003f80u : 0u;   // k=4 slot = 1.0 (bias row)
  if (wgid < nbatch && q == 0) {
    int iu = (wgid << 4) + c;
    b1u0 = pk_bf16(Xg[iu], Yg[iu]); b1u1 = pk_bf16(C1g[iu], C2g[iu]);
  }

  for (int b = wgid; b < nbatch; b += nwaves_total) {
    // ---- layer 1 (K=5 augmented; bias folded into A row 4) ----
    u32 pu[16];
#pragma unroll
    for (int t = 0; t < 8; t++) {
      u32x4 wf = {0u, 0u, 0u, 0u};
      if (q == 0) wf = *(const u32x4*)(lds + LDS_W1 + t * 256 + c * 16);
      f32x4 z = {0.f, 0.f, 0.f, 0.f};
      f32x4 acu = MFMA16(as_frag(wf), mk_frag(b1u0, b1u1, b1w2, 0u), z);
      pu[2*t]   = pk_bf16(fast_tanh(acu[0]), fast_tanh(acu[1]));
      pu[2*t+1] = pk_bf16(fast_tanh(acu[2]), fast_tanh(acu[3]));
    }

    // prefetch next iteration's inputs; HBM latency hides under layers 2-4
    {
      int bn = b + nwaves_total;
      if (bn < nbatch && q == 0) {
        int iu = (bn << 4) + c;
        b1u0 = pk_bf16(Xg[iu], Yg[iu]); b1u1 = pk_bf16(C1g[iu], C2g[iu]);
      }
    }

    // ---- layer 2: registers -> registers ----
    u32 qu[16];
#pragma unroll
    for (int t = 0; t < 8; t++) {
      f32x4 acu = *(const f32x4*)(lds + LDS_B2 + t * 64 + biasaddr);
#pragma unroll
      for (int ks = 0; ks < 4; ks++) {
        bf16x8 aw = *(const bf16x8*)(lds + LDS_W2 + t * 4096 + posA[ks]);
        acu = MFMA16(aw, mk_frag(pu[4*ks], pu[4*ks+1], pu[4*ks+2], pu[4*ks+3]), acu);
      }
      qu[2*t]   = pk_bf16(fast_tanh(acu[0]), fast_tanh(acu[1]));
      qu[2*t+1] = pk_bf16(fast_tanh(acu[2]), fast_tanh(acu[3]));
    }

    // ---- layer 3 fused with layer 4: L3's tile-pair output feeds L4's ks-MFMA
    // immediately, so it never lives as a full 16-word array ----
    f32x4 acu4 = {b4_0, b4_1, 0.f, 0.f};
#pragma unroll
    for (int tp = 0; tp < 4; tp++) {
      u32 pwu[4];
#pragma unroll
      for (int h = 0; h < 2; h++) {
        int t = tp * 2 + h;
        f32x4 acu = *(const f32x4*)(lds + LDS_B3 + t * 64 + biasaddr);
#pragma unroll
        for (int ks = 0; ks < 4; ks++) {
          bf16x8 aw = *(const bf16x8*)(lds + LDS_W3 + t * 4096 + posA[ks]);
          acu = MFMA16(aw, mk_frag(qu[4*ks], qu[4*ks+1], qu[4*ks+2], qu[4*ks+3]), acu);
        }
        pwu[2*h]   = pk_bf16(fast_tanh(acu[0]), fast_tanh(acu[1]));
        pwu[2*h+1] = pk_bf16(fast_tanh(acu[2]), fast_tanh(acu[3]));
      }
      bf16x8 aw4 = *(const bf16x8*)(lds + LDS_W4 + w4addr + tp * 64);
      acu4 = MFMA16(aw4, mk_frag(pwu[0], pwu[1], pwu[2], pwu[3]), acu4);
    }

    // ---- store (rows 0/1 of the padded N=16 tile are the two logits) ----
    if (q == 0) {
      const int pb = b << 4;
      f32x2 ou = {acu4[0], acu4[1]};
      *(f32x2*)(Og + (size_t)(pb + c) * 2) = ou;
    }
  }
}

extern "C" void kernel_launch(void* const* d_in, const int* in_sizes, int n_in,
                              void* d_out, int out_size, void* d_ws, size_t ws_size,
                              hipStream_t stream)
{
  (void)n_in; (void)out_size; (void)d_ws; (void)ws_size;
  const float* X  = (const float*)d_in[0];
  const float* Y  = (const float*)d_in[1];
  const float* C1 = (const float*)d_in[2];
  const float* C2 = (const float*)d_in[3];
  const float* W1 = (const float*)d_in[4];
  const float* B1 = (const float*)d_in[5];
  const float* W2 = (const float*)d_in[6];
  const float* B2 = (const float*)d_in[7];
  const float* W3 = (const float*)d_in[8];
  const float* B3 = (const float*)d_in[9];
  const float* W4 = (const float*)d_in[10];
  const float* B4 = (const float*)d_in[11];
  int npts = in_sizes[0];
  const int nblk = 512;               // 2 WGs/CU (LDS 69120 B each), 8 waves per WG
  const int nwaves = nblk * 8;
  hipLaunchKernelGGL(mlp_fused, dim3(nblk), dim3(512), LDS_TOTAL, stream,
                     X, Y, C1, C2, W1, B1, W2, B2, W3, B3, W4, B4,
                     (float*)d_out, npts, nwaves);
}

// Round 5
// 154.200 us; speedup vs baseline: 2.0170x; 2.0170x over previous
//
#include <hip/hip_runtime.h>
#include <hip/hip_bf16.h>

using u16 = unsigned short;
using u32 = unsigned int;

typedef __attribute__((ext_vector_type(8))) short bf16x8;
typedef __attribute__((ext_vector_type(4))) float f32x4;
typedef __attribute__((ext_vector_type(2))) float f32x2;
typedef __attribute__((ext_vector_type(4))) u32 u32x4;

#define MFMA16(a, b, c) __builtin_amdgcn_mfma_f32_16x16x32_bf16((a), (b), (c), 0, 0, 0)
#define SBAR() __builtin_amdgcn_sched_barrier(0)

union FragU { u32 u[4]; bf16x8 v; u32x4 q; };

__device__ __forceinline__ bf16x8 mk_frag(u32 a, u32 b, u32 c, u32 d) {
  FragU f; f.u[0] = a; f.u[1] = b; f.u[2] = c; f.u[3] = d; return f.v;
}
__device__ __forceinline__ bf16x8 as_frag(u32x4 x) { FragU f; f.q = x; return f.v; }

__device__ __forceinline__ u16 f2bf(float x) {
  __hip_bfloat16 h = __float2bfloat16(x);
  u16 r; __builtin_memcpy(&r, &h, 2); return r;
}

__device__ __forceinline__ u32 pk_bf16(float a, float b) {
  __hip_bfloat162 h = __float22bfloat162_rn(make_float2(a, b));
  u32 r; __builtin_memcpy(&r, &h, 4); return r;
}

__device__ __forceinline__ float fast_tanh(float x) {
  // tanh(x) = 1 - 2/(1 + exp2(x * 2*log2(e)))
  float t = __builtin_amdgcn_exp2f(x * 2.885390081777927f);
  return __builtin_fmaf(-2.0f, __builtin_amdgcn_rcpf(1.0f + t), 1.0f);
}

// Flipped orientation: every layer computes D[hidden][point] with A = W^T, B = activations.
// With contraction order K(ks,8q+j) = 32ks + 16*(j>>2) + 4q + (j&3), the next layer's
// B-fragment is exactly the lane's OWN packed tanh outputs of D-tiles 2ks, 2ks+1:
// activations never leave registers (no LDS hbuf, no shuffles, no repacks).
//
// SPILL DIAGNOSIS (rounds 1-4, measured): the scratch traffic does NOT scale with the
// architectural live set (two-tile ~145 live, one-tile ~52 live: both spill ~0.5 GB at
// cap 128). Cause is the SCHEDULER: each layer is 32 unrolled ds_read_b128 feeding MFMAs,
// and LLVM hoists ds_reads en masse (up to 128 VGPRs of weight fragments in flight),
// spilling activation arrays to scratch to make room. Fix here:
//  - __builtin_amdgcn_sched_barrier(0) after every t-iteration: the scheduler may
//    pipeline within one iteration (4 ds_reads + 4 MFMA + 8 tanh, ~30 transient regs)
//    but cannot hoist the next iteration's loads. Latency hiding moves from register-
//    hungry ILP to TLP (16 waves/CU).
//  - unroll(disable) on the grid-stride b-loop (LLVM x2-unroll doubles live set).

#define LDS_W2 0          // 32768 B
#define LDS_W3 32768      // 32768 B
#define LDS_W4 65536      //   512 B (2 rows x 256)
#define LDS_B2 66048      //   512 B f32[128]
#define LDS_B3 66560      //   512 B f32[128]
#define LDS_W1 67072      //  2048 B (128 rows x 16 B, q==0 A-chunk incl. bias at j=4)
#define LDS_TOTAL 69120   // 2 WGs/CU co-resident (138240 <= 163840)

__global__ void __launch_bounds__(512, 2) mlp_fused(
    const float* __restrict__ Xg, const float* __restrict__ Yg,
    const float* __restrict__ C1g, const float* __restrict__ C2g,
    const float* __restrict__ W1g, const float* __restrict__ B1g,
    const float* __restrict__ W2g, const float* __restrict__ B2g,
    const float* __restrict__ W3g, const float* __restrict__ B3g,
    const float* __restrict__ W4g, const float* __restrict__ B4g,
    float* __restrict__ Og, int npts, int nwaves_total)
{
  extern __shared__ char lds[];
  const int tid = threadIdx.x;

  // ---- stage W2^T / W3^T as K-interleaved, bank-swizzled A-fragments ----
  for (int i = tid; i < 16384; i += 512) {
    int k = i >> 7, n = i & 127;                       // W[k][n], k = hid_in, n = hid_out
    int kc = ((k >> 5) << 2) | ((k >> 2) & 3);         // chunk = 4*ks + q
    int j  = (k & 3) | (((k >> 4) & 1) << 2);          // slot within chunk
    int off = n * 256 + ((kc ^ (n & 15)) << 4) + (j << 1);
    *(u16*)(lds + LDS_W2 + off) = f2bf(W2g[i]);
    *(u16*)(lds + LDS_W3 + off) = f2bf(W3g[i]);
  }
  if (tid < 256) {                                     // W4 is [128][2] row-major
    int k = tid >> 1, o = tid & 1;
    int kc = ((k >> 5) << 2) | ((k >> 2) & 3);
    int j  = (k & 3) | (((k >> 4) & 1) << 2);
    *(u16*)(lds + LDS_W4 + o * 256 + (kc << 4) + (j << 1)) = f2bf(W4g[tid]);
  }
  if (tid < 128) {
    ((float*)(lds + LDS_B2))[tid] = B2g[tid];
    ((float*)(lds + LDS_B3))[tid] = B3g[tid];
    // W1 augmented A-chunk (q==0 only): j=0..3 -> W1[0..3][n], j=4 -> b1[n]
    u32* w1r = (u32*)(lds + LDS_W1 + tid * 16);
    w1r[0] = pk_bf16(W1g[tid],       W1g[128 + tid]);
    w1r[1] = pk_bf16(W1g[256 + tid], W1g[384 + tid]);
    w1r[2] = pk_bf16(B1g[tid], 0.f);
    w1r[3] = 0u;
  }
  __syncthreads();

  const int wave = tid >> 6;
  const int lane = tid & 63;
  const int q = lane >> 4;
  const int c = lane & 15;
  const int wgid = blockIdx.x * 8 + wave;

  int posA[4];
#pragma unroll
  for (int ks = 0; ks < 4; ks++) posA[ks] = c * 256 + (((ks * 4 + q) ^ c) << 4);
  const int biasaddr = q * 16;
  const int w4addr = (c & 1) * 256 + q * 16;   // c>=2 lanes duplicate rows -> unused D rows
  const float b4_0 = B4g[0], b4_1 = B4g[1];

  const int nbatch = npts >> 4;   // ONE 16-point tile per wave-iteration

  // software-pipelined input fetch (q==0 lanes only; packed at arrival: 2 live u32)
  u32 b1u0 = 0, b1u1 = 0;
  const u32 b1w2 = (q == 0) ? 0x00003f80u : 0u;   // k=4 slot = 1.0 (bias row)
  if (wgid < nbatch && q == 0) {
    int iu = (wgid << 4) + c;
    b1u0 = pk_bf16(Xg[iu], Yg[iu]); b1u1 = pk_bf16(C1g[iu], C2g[iu]);
  }

#pragma clang loop unroll(disable)
  for (int b = wgid; b < nbatch; b += nwaves_total) {
    // ---- layer 1 (K=5 augmented; bias folded into A row 4) ----
    u32 pu[16];
#pragma unroll
    for (int t = 0; t < 8; t++) {
      u32x4 wf = {0u, 0u, 0u, 0u};
      if (q == 0) wf = *(const u32x4*)(lds + LDS_W1 + t * 256 + c * 16);
      f32x4 z = {0.f, 0.f, 0.f, 0.f};
      f32x4 acu = MFMA16(as_frag(wf), mk_frag(b1u0, b1u1, b1w2, 0u), z);
      pu[2*t]   = pk_bf16(fast_tanh(acu[0]), fast_tanh(acu[1]));
      pu[2*t+1] = pk_bf16(fast_tanh(acu[2]), fast_tanh(acu[3]));
      SBAR();   // fence: no cross-iteration ds_read hoisting (spill control)
    }

    // prefetch next iteration's inputs; HBM latency hides under layers 2-4
    {
      int bn = b + nwaves_total;
      if (bn < nbatch && q == 0) {
        int iu = (bn << 4) + c;
        b1u0 = pk_bf16(Xg[iu], Yg[iu]); b1u1 = pk_bf16(C1g[iu], C2g[iu]);
      }
    }
    SBAR();

    // ---- layer 2: registers -> registers ----
    u32 qu[16];
#pragma unroll
    for (int t = 0; t < 8; t++) {
      f32x4 acu = *(const f32x4*)(lds + LDS_B2 + t * 64 + biasaddr);
#pragma unroll
      for (int ks = 0; ks < 4; ks++) {
        bf16x8 aw = *(const bf16x8*)(lds + LDS_W2 + t * 4096 + posA[ks]);
        acu = MFMA16(aw, mk_frag(pu[4*ks], pu[4*ks+1], pu[4*ks+2], pu[4*ks+3]), acu);
      }
      qu[2*t]   = pk_bf16(fast_tanh(acu[0]), fast_tanh(acu[1]));
      qu[2*t+1] = pk_bf16(fast_tanh(acu[2]), fast_tanh(acu[3]));
      SBAR();   // fence: bounds in-flight weight fragments to one t-iteration
    }

    // ---- layer 3 fused with layer 4: L3's tile-pair output feeds L4's ks-MFMA
    // immediately, so it never lives as a full 16-word array ----
    f32x4 acu4 = {b4_0, b4_1, 0.f, 0.f};
#pragma unroll
    for (int tp = 0; tp < 4; tp++) {
      u32 pwu[4];
#pragma unroll
      for (int h = 0; h < 2; h++) {
        int t = tp * 2 + h;
        f32x4 acu = *(const f32x4*)(lds + LDS_B3 + t * 64 + biasaddr);
#pragma unroll
        for (int ks = 0; ks < 4; ks++) {
          bf16x8 aw = *(const bf16x8*)(lds + LDS_W3 + t * 4096 + posA[ks]);
          acu = MFMA16(aw, mk_frag(qu[4*ks], qu[4*ks+1], qu[4*ks+2], qu[4*ks+3]), acu);
        }
        pwu[2*h]   = pk_bf16(fast_tanh(acu[0]), fast_tanh(acu[1]));
        pwu[2*h+1] = pk_bf16(fast_tanh(acu[2]), fast_tanh(acu[3]));
        SBAR();
      }
      bf16x8 aw4 = *(const bf16x8*)(lds + LDS_W4 + w4addr + tp * 64);
      acu4 = MFMA16(aw4, mk_frag(pwu[0], pwu[1], pwu[2], pwu[3]), acu4);
      SBAR();
    }

    // ---- store (rows 0/1 of the padded N=16 tile are the two logits) ----
    if (q == 0) {
      const int pb = b << 4;
      f32x2 ou = {acu4[0], acu4[1]};
      *(f32x2*)(Og + (size_t)(pb + c) * 2) = ou;
    }
  }
}

extern "C" void kernel_launch(void* const* d_in, const int* in_sizes, int n_in,
                              void* d_out, int out_size, void* d_ws, size_t ws_size,
                              hipStream_t stream)
{
  (void)n_in; (void)out_size; (void)d_ws; (void)ws_size;
  const float* X  = (const float*)d_in[0];
  const float* Y  = (const float*)d_in[1];
  const float* C1 = (const float*)d_in[2];
  const float* C2 = (const float*)d_in[3];
  const float* W1 = (const float*)d_in[4];
  const float* B1 = (const float*)d_in[5];
  const float* W2 = (const float*)d_in[6];
  const float* B2 = (const float*)d_in[7];
  const float* W3 = (const float*)d_in[8];
  const float* B3 = (const float*)d_in[9];
  const float* W4 = (const float*)d_in[10];
  const float* B4 = (const float*)d_in[11];
  int npts = in_sizes[0];
  const int nblk = 512;               // 2 WGs/CU (LDS 69120 B each), 8 waves per WG
  const int nwaves = nblk * 8;
  hipLaunchKernelGGL(mlp_fused, dim3(nblk), dim3(512), LDS_TOTAL, stream,
                     X, Y, C1, C2, W1, B1, W2, B2, W3, B3, W4, B4,
                     (float*)d_out, npts, nwaves);
}

// Round 6
// 148.812 us; speedup vs baseline: 2.0901x; 1.0362x over previous
//
#include <hip/hip_runtime.h>
#include <hip/hip_bf16.h>

using u16 = unsigned short;
using u32 = unsigned int;

typedef __attribute__((ext_vector_type(8))) short bf16x8;
typedef __attribute__((ext_vector_type(4))) float f32x4;
typedef __attribute__((ext_vector_type(2))) float f32x2;
typedef __attribute__((ext_vector_type(4))) u32 u32x4;

#define MFMA16(a, b, c) __builtin_amdgcn_mfma_f32_16x16x32_bf16((a), (b), (c), 0, 0, 0)
#define SBAR() __builtin_amdgcn_sched_barrier(0)

union FragU { u32 u[4]; bf16x8 v; u32x4 q; };

__device__ __forceinline__ bf16x8 mk_frag(u32 a, u32 b, u32 c, u32 d) {
  FragU f; f.u[0] = a; f.u[1] = b; f.u[2] = c; f.u[3] = d; return f.v;
}
__device__ __forceinline__ bf16x8 as_frag(u32x4 x) { FragU f; f.q = x; return f.v; }

__device__ __forceinline__ u16 f2bf(float x) {
  __hip_bfloat16 h = __float2bfloat16(x);
  u16 r; __builtin_memcpy(&r, &h, 2); return r;
}

__device__ __forceinline__ u32 pk_bf16(float a, float b) {
  __hip_bfloat162 h = __float22bfloat162_rn(make_float2(a, b));
  u32 r; __builtin_memcpy(&r, &h, 4); return r;
}

__device__ __forceinline__ float fast_tanh(float x) {
  // tanh(x) = 1 - 2/(1 + exp2(x * 2*log2(e)))
  float t = __builtin_amdgcn_exp2f(x * 2.885390081777927f);
  return __builtin_fmaf(-2.0f, __builtin_amdgcn_rcpf(1.0f + t), 1.0f);
}

// Flipped orientation: every layer computes D[hidden][point] with A = W^T, B = activations.
// With contraction order K(ks,8q+j) = 32ks + 16*(j>>2) + 4q + (j&3), the next layer's
// B-fragment is exactly the lane's OWN packed tanh outputs of D-tiles 2ks, 2ks+1:
// activations never leave registers (no LDS hbuf, no shuffles, no repacks).
//
// SPILL HISTORY (rounds 1-5, measured on this toolchain):
//  - Scratch traffic does NOT scale with the architectural live set; the cause was the
//    LLVM scheduler hoisting unrolled ds_read_b128 chains en masse (hundreds of MB of
//    FETCH at cap 128 even with a ~52-word live set).
//  - sched_barrier(0) after every t-iteration fixed it: FETCH 513 MB -> 4.7 MB,
//    245 -> 90 us, but VGPR_Count fell to 32: fences left ILP on the table
//    (VALUBusy 60%).
//  - This round: spend the ~96 spare VGPRs on the two-tile (u/v) scheme WITH fences.
//    Each fence region: 4 ds_read -> 8 MFMA + 32 tanh; LDS ops and loop overhead per
//    point halve. Peak live ~116 < 128. FETCH_SIZE is the spill tell (<= ~6 MB = pass).

#define LDS_W2 0          // 32768 B
#define LDS_W3 32768      // 32768 B
#define LDS_W4 65536      //   512 B (2 rows x 256)
#define LDS_B2 66048      //   512 B f32[128]
#define LDS_B3 66560      //   512 B f32[128]
#define LDS_W1 67072      //  2048 B (128 rows x 16 B, q==0 A-chunk incl. bias at j=4)
#define LDS_TOTAL 69120   // 2 WGs/CU co-resident (138240 <= 163840)

__global__ void __launch_bounds__(512, 2) mlp_fused(
    const float* __restrict__ Xg, const float* __restrict__ Yg,
    const float* __restrict__ C1g, const float* __restrict__ C2g,
    const float* __restrict__ W1g, const float* __restrict__ B1g,
    const float* __restrict__ W2g, const float* __restrict__ B2g,
    const float* __restrict__ W3g, const float* __restrict__ B3g,
    const float* __restrict__ W4g, const float* __restrict__ B4g,
    float* __restrict__ Og, int npts, int nwaves_total)
{
  extern __shared__ char lds[];
  const int tid = threadIdx.x;

  // ---- stage W2^T / W3^T as K-interleaved, bank-swizzled A-fragments ----
  for (int i = tid; i < 16384; i += 512) {
    int k = i >> 7, n = i & 127;                       // W[k][n], k = hid_in, n = hid_out
    int kc = ((k >> 5) << 2) | ((k >> 2) & 3);         // chunk = 4*ks + q
    int j  = (k & 3) | (((k >> 4) & 1) << 2);          // slot within chunk
    int off = n * 256 + ((kc ^ (n & 15)) << 4) + (j << 1);
    *(u16*)(lds + LDS_W2 + off) = f2bf(W2g[i]);
    *(u16*)(lds + LDS_W3 + off) = f2bf(W3g[i]);
  }
  if (tid < 256) {                                     // W4 is [128][2] row-major
    int k = tid >> 1, o = tid & 1;
    int kc = ((k >> 5) << 2) | ((k >> 2) & 3);
    int j  = (k & 3) | (((k >> 4) & 1) << 2);
    *(u16*)(lds + LDS_W4 + o * 256 + (kc << 4) + (j << 1)) = f2bf(W4g[tid]);
  }
  if (tid < 128) {
    ((float*)(lds + LDS_B2))[tid] = B2g[tid];
    ((float*)(lds + LDS_B3))[tid] = B3g[tid];
    // W1 augmented A-chunk (q==0 only): j=0..3 -> W1[0..3][n], j=4 -> b1[n]
    u32* w1r = (u32*)(lds + LDS_W1 + tid * 16);
    w1r[0] = pk_bf16(W1g[tid],       W1g[128 + tid]);
    w1r[1] = pk_bf16(W1g[256 + tid], W1g[384 + tid]);
    w1r[2] = pk_bf16(B1g[tid], 0.f);
    w1r[3] = 0u;
  }
  __syncthreads();

  const int wave = tid >> 6;
  const int lane = tid & 63;
  const int q = lane >> 4;
  const int c = lane & 15;
  const int wgid = blockIdx.x * 8 + wave;

  int posA[4];
#pragma unroll
  for (int ks = 0; ks < 4; ks++) posA[ks] = c * 256 + (((ks * 4 + q) ^ c) << 4);
  const int biasaddr = q * 16;
  const int w4addr = (c & 1) * 256 + q * 16;   // c>=2 lanes duplicate rows -> unused D rows
  const float b4_0 = B4g[0], b4_1 = B4g[1];

  const int nbatch = npts >> 5;   // 32 points (2 tiles of 16) per wave-iteration

  // software-pipelined input fetch (q==0 lanes only; packed at arrival: 4 live u32)
  u32 b1u0 = 0, b1u1 = 0, b1v0 = 0, b1v1 = 0;
  const u32 b1w2 = (q == 0) ? 0x00003f80u : 0u;   // k=4 slot = 1.0 (bias row)
  if (wgid < nbatch && q == 0) {
    int iu = (wgid << 5) + c, iv = iu + 16;
    b1u0 = pk_bf16(Xg[iu], Yg[iu]); b1u1 = pk_bf16(C1g[iu], C2g[iu]);
    b1v0 = pk_bf16(Xg[iv], Yg[iv]); b1v1 = pk_bf16(C1g[iv], C2g[iv]);
  }

#pragma clang loop unroll(disable)
  for (int b = wgid; b < nbatch; b += nwaves_total) {
    // ---- layer 1 (K=5 augmented; bias folded into A row 4) ----
    u32 pu[16], pv[16];
#pragma unroll
    for (int t = 0; t < 8; t++) {
      u32x4 wf = {0u, 0u, 0u, 0u};
      if (q == 0) wf = *(const u32x4*)(lds + LDS_W1 + t * 256 + c * 16);
      f32x4 z = {0.f, 0.f, 0.f, 0.f};
      f32x4 acu = MFMA16(as_frag(wf), mk_frag(b1u0, b1u1, b1w2, 0u), z);
      f32x4 acv = MFMA16(as_frag(wf), mk_frag(b1v0, b1v1, b1w2, 0u), z);
      pu[2*t]   = pk_bf16(fast_tanh(acu[0]), fast_tanh(acu[1]));
      pu[2*t+1] = pk_bf16(fast_tanh(acu[2]), fast_tanh(acu[3]));
      pv[2*t]   = pk_bf16(fast_tanh(acv[0]), fast_tanh(acv[1]));
      pv[2*t+1] = pk_bf16(fast_tanh(acv[2]), fast_tanh(acv[3]));
      SBAR();   // fence: no cross-iteration ds_read hoisting (spill control)
    }

    // prefetch next iteration's inputs; HBM latency hides under layers 2-4
    {
      int bn = b + nwaves_total;
      if (bn < nbatch && q == 0) {
        int iu = (bn << 5) + c, iv = iu + 16;
        b1u0 = pk_bf16(Xg[iu], Yg[iu]); b1u1 = pk_bf16(C1g[iu], C2g[iu]);
        b1v0 = pk_bf16(Xg[iv], Yg[iv]); b1v1 = pk_bf16(C1g[iv], C2g[iv]);
      }
    }
    SBAR();

    // ---- layer 2: registers -> registers (each weight frag feeds BOTH tiles) ----
    u32 qu[16], qv[16];
#pragma unroll
    for (int t = 0; t < 8; t++) {
      f32x4 bi = *(const f32x4*)(lds + LDS_B2 + t * 64 + biasaddr);
      f32x4 acu = bi, acv = bi;
#pragma unroll
      for (int ks = 0; ks < 4; ks++) {
        bf16x8 aw = *(const bf16x8*)(lds + LDS_W2 + t * 4096 + posA[ks]);
        acu = MFMA16(aw, mk_frag(pu[4*ks], pu[4*ks+1], pu[4*ks+2], pu[4*ks+3]), acu);
        acv = MFMA16(aw, mk_frag(pv[4*ks], pv[4*ks+1], pv[4*ks+2], pv[4*ks+3]), acv);
      }
      qu[2*t]   = pk_bf16(fast_tanh(acu[0]), fast_tanh(acu[1]));
      qu[2*t+1] = pk_bf16(fast_tanh(acu[2]), fast_tanh(acu[3]));
      qv[2*t]   = pk_bf16(fast_tanh(acv[0]), fast_tanh(acv[1]));
      qv[2*t+1] = pk_bf16(fast_tanh(acv[2]), fast_tanh(acv[3]));
      SBAR();   // fence: bounds in-flight weight fragments to one t-iteration
    }

    // ---- layer 3 fused with layer 4: L3's tile-pair output feeds L4's ks-MFMA
    // immediately, so it never lives as a full 32-word array ----
    f32x4 acu4 = {b4_0, b4_1, 0.f, 0.f};
    f32x4 acv4 = acu4;
#pragma unroll
    for (int tp = 0; tp < 4; tp++) {
      u32 pwu[4], pwv[4];
#pragma unroll
      for (int h = 0; h < 2; h++) {
        int t = tp * 2 + h;
        f32x4 bi = *(const f32x4*)(lds + LDS_B3 + t * 64 + biasaddr);
        f32x4 acu = bi, acv = bi;
#pragma unroll
        for (int ks = 0; ks < 4; ks++) {
          bf16x8 aw = *(const bf16x8*)(lds + LDS_W3 + t * 4096 + posA[ks]);
          acu = MFMA16(aw, mk_frag(qu[4*ks], qu[4*ks+1], qu[4*ks+2], qu[4*ks+3]), acu);
          acv = MFMA16(aw, mk_frag(qv[4*ks], qv[4*ks+1], qv[4*ks+2], qv[4*ks+3]), acv);
        }
        pwu[2*h]   = pk_bf16(fast_tanh(acu[0]), fast_tanh(acu[1]));
        pwu[2*h+1] = pk_bf16(fast_tanh(acu[2]), fast_tanh(acu[3]));
        pwv[2*h]   = pk_bf16(fast_tanh(acv[0]), fast_tanh(acv[1]));
        pwv[2*h+1] = pk_bf16(fast_tanh(acv[2]), fast_tanh(acv[3]));
        SBAR();
      }
      bf16x8 aw4 = *(const bf16x8*)(lds + LDS_W4 + w4addr + tp * 64);
      acu4 = MFMA16(aw4, mk_frag(pwu[0], pwu[1], pwu[2], pwu[3]), acu4);
      acv4 = MFMA16(aw4, mk_frag(pwv[0], pwv[1], pwv[2], pwv[3]), acv4);
      SBAR();
    }

    // ---- store (rows 0/1 of the padded N=16 tile are the two logits) ----
    if (q == 0) {
      const int pb = b << 5;
      f32x2 ou = {acu4[0], acu4[1]}, ov = {acv4[0], acv4[1]};
      *(f32x2*)(Og + (size_t)(pb + c) * 2)      = ou;
      *(f32x2*)(Og + (size_t)(pb + 16 + c) * 2) = ov;
    }
  }
}

extern "C" void kernel_launch(void* const* d_in, const int* in_sizes, int n_in,
                              void* d_out, int out_size, void* d_ws, size_t ws_size,
                              hipStream_t stream)
{
  (void)n_in; (void)out_size; (void)d_ws; (void)ws_size;
  const float* X  = (const float*)d_in[0];
  const float* Y  = (const float*)d_in[1];
  const float* C1 = (const float*)d_in[2];
  const float* C2 = (const float*)d_in[3];
  const float* W1 = (const float*)d_in[4];
  const float* B1 = (const float*)d_in[5];
  const float* W2 = (const float*)d_in[6];
  const float* B2 = (const float*)d_in[7];
  const float* W3 = (const float*)d_in[8];
  const float* B3 = (const float*)d_in[9];
  const float* W4 = (const float*)d_in[10];
  const float* B4 = (const float*)d_in[11];
  int npts = in_sizes[0];
  const int nblk = 512;               // 2 WGs/CU (LDS 69120 B each), 8 waves per WG
  const int nwaves = nblk * 8;
  hipLaunchKernelGGL(mlp_fused, dim3(nblk), dim3(512), LDS_TOTAL, stream,
                     X, Y, C1, C2, W1, B1, W2, B2, W3, B3, W4, B4,
                     (float*)d_out, npts, nwaves);
}

// Round 7
// 148.401 us; speedup vs baseline: 2.0958x; 1.0028x over previous
//
#include <hip/hip_runtime.h>
#include <hip/hip_bf16.h>

using u16 = unsigned short;
using u32 = unsigned int;

typedef __attribute__((ext_vector_type(8))) short bf16x8;
typedef __attribute__((ext_vector_type(4))) float f32x4;
typedef __attribute__((ext_vector_type(2))) float f32x2;
typedef __attribute__((ext_vector_type(4))) u32 u32x4;

#define MFMA16(a, b, c) __builtin_amdgcn_mfma_f32_16x16x32_bf16((a), (b), (c), 0, 0, 0)
// Selective fence: ALU|VALU|SALU|MFMA (0x0F) MAY cross; all DS/VMEM may NOT.
// Blocks the mass ds_read hoisting that caused 0.5 GB scratch spill (rounds 2-4),
// while letting tanh/pack chains interleave across region boundaries (round 6 left
// VALUBusy at 60% with mask 0).
#define SBARM() __builtin_amdgcn_sched_barrier(0x0F)

union FragU { u32 u[4]; bf16x8 v; u32x4 q; };

__device__ __forceinline__ bf16x8 mk_frag(u32 a, u32 b, u32 c, u32 d) {
  FragU f; f.u[0] = a; f.u[1] = b; f.u[2] = c; f.u[3] = d; return f.v;
}
__device__ __forceinline__ bf16x8 as_frag(u32x4 x) { FragU f; f.q = x; return f.v; }

__device__ __forceinline__ u16 f2bf(float x) {
  __hip_bfloat16 h = __float2bfloat16(x);
  u16 r; __builtin_memcpy(&r, &h, 2); return r;
}

__device__ __forceinline__ u32 pk_bf16(float a, float b) {
  __hip_bfloat162 h = __float22bfloat162_rn(make_float2(a, b));
  u32 r; __builtin_memcpy(&r, &h, 4); return r;
}

__device__ __forceinline__ float fast_tanh(float x) {
  // tanh(x) = 1 - 2/(1 + exp2(x * 2*log2(e)))
  float t = __builtin_amdgcn_exp2f(x * 2.885390081777927f);
  return __builtin_fmaf(-2.0f, __builtin_amdgcn_rcpf(1.0f + t), 1.0f);
}

// Flipped orientation: every layer computes D[hidden][point] with A = W^T, B = activations.
// With contraction order K(ks,8q+j) = 32ks + 16*(j>>2) + 4q + (j&3), the next layer's
// B-fragment is exactly the lane's OWN packed tanh outputs of D-tiles 2ks, 2ks+1:
// activations never leave registers (no LDS hbuf, no shuffles, no repacks).
//
// SPILL/FENCE HISTORY (rounds 1-6, measured on this toolchain):
//  - Scratch traffic does NOT scale with the architectural live set; cause = LLVM
//    scheduler hoisting unrolled ds_read_b128 chains en masse at cap 128.
//  - sched_barrier(0) per t-iteration fixed the spill (FETCH 513 MB -> 4.7 MB, -> 90 us)
//    but blocked ALL cross-region overlap: VGPR fell to 32, VALUBusy stuck at 60%.
//  - Two-tile u/v + fences: 85 us, VGPR 52, still 60% busy.
//  - This round: mask-0x0F fences (VALU/MFMA cross OK, memory pinned) + decoupled
//    prefetch (raw floats held, packed next iteration => vmcnt wait 3 layers after
//    issue). VALU floor ~35-40 us; target 58-68 us at ~80% busy.

#define LDS_W2 0          // 32768 B
#define LDS_W3 32768      // 32768 B
#define LDS_W4 65536      //   512 B (2 rows x 256)
#define LDS_B2 66048      //   512 B f32[128]
#define LDS_B3 66560      //   512 B f32[128]
#define LDS_W1 67072      //  2048 B (128 rows x 16 B, q==0 A-chunk incl. bias at j=4)
#define LDS_TOTAL 69120   // 2 WGs/CU co-resident (138240 <= 163840)

__global__ void __launch_bounds__(512, 2) mlp_fused(
    const float* __restrict__ Xg, const float* __restrict__ Yg,
    const float* __restrict__ C1g, const float* __restrict__ C2g,
    const float* __restrict__ W1g, const float* __restrict__ B1g,
    const float* __restrict__ W2g, const float* __restrict__ B2g,
    const float* __restrict__ W3g, const float* __restrict__ B3g,
    const float* __restrict__ W4g, const float* __restrict__ B4g,
    float* __restrict__ Og, int npts, int nwaves_total)
{
  extern __shared__ char lds[];
  const int tid = threadIdx.x;

  // ---- stage W2^T / W3^T as K-interleaved, bank-swizzled A-fragments ----
  for (int i = tid; i < 16384; i += 512) {
    int k = i >> 7, n = i & 127;                       // W[k][n], k = hid_in, n = hid_out
    int kc = ((k >> 5) << 2) | ((k >> 2) & 3);         // chunk = 4*ks + q
    int j  = (k & 3) | (((k >> 4) & 1) << 2);          // slot within chunk
    int off = n * 256 + ((kc ^ (n & 15)) << 4) + (j << 1);
    *(u16*)(lds + LDS_W2 + off) = f2bf(W2g[i]);
    *(u16*)(lds + LDS_W3 + off) = f2bf(W3g[i]);
  }
  if (tid < 256) {                                     // W4 is [128][2] row-major
    int k = tid >> 1, o = tid & 1;
    int kc = ((k >> 5) << 2) | ((k >> 2) & 3);
    int j  = (k & 3) | (((k >> 4) & 1) << 2);
    *(u16*)(lds + LDS_W4 + o * 256 + (kc << 4) + (j << 1)) = f2bf(W4g[tid]);
  }
  if (tid < 128) {
    ((float*)(lds + LDS_B2))[tid] = B2g[tid];
    ((float*)(lds + LDS_B3))[tid] = B3g[tid];
    // W1 augmented A-chunk (q==0 only): j=0..3 -> W1[0..3][n], j=4 -> b1[n]
    u32* w1r = (u32*)(lds + LDS_W1 + tid * 16);
    w1r[0] = pk_bf16(W1g[tid],       W1g[128 + tid]);
    w1r[1] = pk_bf16(W1g[256 + tid], W1g[384 + tid]);
    w1r[2] = pk_bf16(B1g[tid], 0.f);
    w1r[3] = 0u;
  }
  __syncthreads();

  const int wave = tid >> 6;
  const int lane = tid & 63;
  const int q = lane >> 4;
  const int c = lane & 15;
  const int wgid = blockIdx.x * 8 + wave;

  int posA[4];
#pragma unroll
  for (int ks = 0; ks < 4; ks++) posA[ks] = c * 256 + (((ks * 4 + q) ^ c) << 4);
  const int biasaddr = q * 16;
  const int w4addr = (c & 1) * 256 + q * 16;   // c>=2 lanes duplicate rows -> unused D rows
  const float b4_0 = B4g[0], b4_1 = B4g[1];

  const int nbatch = npts >> 5;   // 32 points (2 tiles of 16) per wave-iteration

  // software-pipelined input fetch (q==0 lanes only): raw floats stay live across
  // layers 2-4; packed to bf16 at the TOP of their own iteration so the vmcnt wait
  // lands ~3 layers after issue.
  float fxu = 0.f, fyu = 0.f, f1u = 0.f, f2u = 0.f;
  float fxv = 0.f, fyv = 0.f, f1v = 0.f, f2v = 0.f;
  const u32 b1w2 = (q == 0) ? 0x00003f80u : 0u;   // k=4 slot = 1.0 (bias row)
  if (wgid < nbatch && q == 0) {
    int iu = (wgid << 5) + c, iv = iu + 16;
    fxu = Xg[iu]; fyu = Yg[iu]; f1u = C1g[iu]; f2u = C2g[iu];
    fxv = Xg[iv]; fyv = Yg[iv]; f1v = C1g[iv]; f2v = C2g[iv];
  }

#pragma clang loop unroll(disable)
  for (int b = wgid; b < nbatch; b += nwaves_total) {
    // ---- layer 1 (K=5 augmented; bias folded into A row 4) ----
    const u32 b1u0 = pk_bf16(fxu, fyu), b1u1 = pk_bf16(f1u, f2u);
    const u32 b1v0 = pk_bf16(fxv, fyv), b1v1 = pk_bf16(f1v, f2v);
    u32 pu[16], pv[16];
#pragma unroll
    for (int t = 0; t < 8; t++) {
      u32x4 wf = {0u, 0u, 0u, 0u};
      if (q == 0) wf = *(const u32x4*)(lds + LDS_W1 + t * 256 + c * 16);
      f32x4 z = {0.f, 0.f, 0.f, 0.f};
      f32x4 acu = MFMA16(as_frag(wf), mk_frag(b1u0, b1u1, b1w2, 0u), z);
      f32x4 acv = MFMA16(as_frag(wf), mk_frag(b1v0, b1v1, b1w2, 0u), z);
      pu[2*t]   = pk_bf16(fast_tanh(acu[0]), fast_tanh(acu[1]));
      pu[2*t+1] = pk_bf16(fast_tanh(acu[2]), fast_tanh(acu[3]));
      pv[2*t]   = pk_bf16(fast_tanh(acv[0]), fast_tanh(acv[1]));
      pv[2*t+1] = pk_bf16(fast_tanh(acv[2]), fast_tanh(acv[3]));
      SBARM();   // fence: ds_reads pinned to their region; VALU/MFMA may interleave
    }

    // prefetch next iteration's inputs; vmcnt wait deferred to next iteration's top
    {
      int bn = b + nwaves_total;
      if (bn < nbatch && q == 0) {
        int iu = (bn << 5) + c, iv = iu + 16;
        fxu = Xg[iu]; fyu = Yg[iu]; f1u = C1g[iu]; f2u = C2g[iu];
        fxv = Xg[iv]; fyv = Yg[iv]; f1v = C1g[iv]; f2v = C2g[iv];
      }
    }
    SBARM();

    // ---- layer 2: registers -> registers (each weight frag feeds BOTH tiles) ----
    u32 qu[16], qv[16];
#pragma unroll
    for (int t = 0; t < 8; t++) {
      f32x4 bi = *(const f32x4*)(lds + LDS_B2 + t * 64 + biasaddr);
      f32x4 acu = bi, acv = bi;
#pragma unroll
      for (int ks = 0; ks < 4; ks++) {
        bf16x8 aw = *(const bf16x8*)(lds + LDS_W2 + t * 4096 + posA[ks]);
        acu = MFMA16(aw, mk_frag(pu[4*ks], pu[4*ks+1], pu[4*ks+2], pu[4*ks+3]), acu);
        acv = MFMA16(aw, mk_frag(pv[4*ks], pv[4*ks+1], pv[4*ks+2], pv[4*ks+3]), acv);
      }
      qu[2*t]   = pk_bf16(fast_tanh(acu[0]), fast_tanh(acu[1]));
      qu[2*t+1] = pk_bf16(fast_tanh(acu[2]), fast_tanh(acu[3]));
      qv[2*t]   = pk_bf16(fast_tanh(acv[0]), fast_tanh(acv[1]));
      qv[2*t+1] = pk_bf16(fast_tanh(acv[2]), fast_tanh(acv[3]));
      SBARM();   // fence: bounds in-flight weight fragments to one t-iteration
    }

    // ---- layer 3 fused with layer 4: L3's tile-pair output feeds L4's ks-MFMA
    // immediately, so it never lives as a full 32-word array ----
    f32x4 acu4 = {b4_0, b4_1, 0.f, 0.f};
    f32x4 acv4 = acu4;
#pragma unroll
    for (int tp = 0; tp < 4; tp++) {
      u32 pwu[4], pwv[4];
#pragma unroll
      for (int h = 0; h < 2; h++) {
        int t = tp * 2 + h;
        f32x4 bi = *(const f32x4*)(lds + LDS_B3 + t * 64 + biasaddr);
        f32x4 acu = bi, acv = bi;
#pragma unroll
        for (int ks = 0; ks < 4; ks++) {
          bf16x8 aw = *(const bf16x8*)(lds + LDS_W3 + t * 4096 + posA[ks]);
          acu = MFMA16(aw, mk_frag(qu[4*ks], qu[4*ks+1], qu[4*ks+2], qu[4*ks+3]), acu);
          acv = MFMA16(aw, mk_frag(qv[4*ks], qv[4*ks+1], qv[4*ks+2], qv[4*ks+3]), acv);
        }
        pwu[2*h]   = pk_bf16(fast_tanh(acu[0]), fast_tanh(acu[1]));
        pwu[2*h+1] = pk_bf16(fast_tanh(acu[2]), fast_tanh(acu[3]));
        pwv[2*h]   = pk_bf16(fast_tanh(acv[0]), fast_tanh(acv[1]));
        pwv[2*h+1] = pk_bf16(fast_tanh(acv[2]), fast_tanh(acv[3]));
        SBARM();
      }
      bf16x8 aw4 = *(const bf16x8*)(lds + LDS_W4 + w4addr + tp * 64);
      acu4 = MFMA16(aw4, mk_frag(pwu[0], pwu[1], pwu[2], pwu[3]), acu4);
      acv4 = MFMA16(aw4, mk_frag(pwv[0], pwv[1], pwv[2], pwv[3]), acv4);
      SBARM();
    }

    // ---- store (rows 0/1 of the padded N=16 tile are the two logits) ----
    if (q == 0) {
      const int pb = b << 5;
      f32x2 ou = {acu4[0], acu4[1]}, ov = {acv4[0], acv4[1]};
      *(f32x2*)(Og + (size_t)(pb + c) * 2)      = ou;
      *(f32x2*)(Og + (size_t)(pb + 16 + c) * 2) = ov;
    }
  }
}

extern "C" void kernel_launch(void* const* d_in, const int* in_sizes, int n_in,
                              void* d_out, int out_size, void* d_ws, size_t ws_size,
                              hipStream_t stream)
{
  (void)n_in; (void)out_size; (void)d_ws; (void)ws_size;
  const float* X  = (const float*)d_in[0];
  const float* Y  = (const float*)d_in[1];
  const float* C1 = (const float*)d_in[2];
  const float* C2 = (const float*)d_in[3];
  const float* W1 = (const float*)d_in[4];
  const float* B1 = (const float*)d_in[5];
  const float* W2 = (const float*)d_in[6];
  const float* B2 = (const float*)d_in[7];
  const float* W3 = (const float*)d_in[8];
  const float* B3 = (const float*)d_in[9];
  const float* W4 = (const float*)d_in[10];
  const float* B4 = (const float*)d_in[11];
  int npts = in_sizes[0];
  const int nblk = 512;               // 2 WGs/CU (LDS 69120 B each), 8 waves per WG
  const int nwaves = nblk * 8;
  hipLaunchKernelGGL(mlp_fused, dim3(nblk), dim3(512), LDS_TOTAL, stream,
                     X, Y, C1, C2, W1, B1, W2, B2, W3, B3, W4, B4,
                     (float*)d_out, npts, nwaves);
}

// Round 8
// 146.967 us; speedup vs baseline: 2.1163x; 1.0098x over previous
//
#include <hip/hip_runtime.h>
#include <hip/hip_bf16.h>

using u16 = unsigned short;
using u32 = unsigned int;

typedef __attribute__((ext_vector_type(8))) short bf16x8;
typedef __attribute__((ext_vector_type(4))) float f32x4;
typedef __attribute__((ext_vector_type(2))) float f32x2;
typedef __attribute__((ext_vector_type(4))) u32 u32x4;

#define MFMA16(a, b, c) __builtin_amdgcn_mfma_f32_16x16x32_bf16((a), (b), (c), 0, 0, 0)
// Selective fence: ALU|VALU|SALU|MFMA (0x0F) MAY cross; all DS/VMEM may NOT.
// Blocks the mass ds_read hoisting that caused 0.5 GB scratch spill (rounds 2-4).
#define SBARM() __builtin_amdgcn_sched_barrier(0x0F)

union FragU { u32 u[4]; bf16x8 v; u32x4 q; };

__device__ __forceinline__ bf16x8 mk_frag(u32 a, u32 b, u32 c, u32 d) {
  FragU f; f.u[0] = a; f.u[1] = b; f.u[2] = c; f.u[3] = d; return f.v;
}
__device__ __forceinline__ bf16x8 as_frag(u32x4 x) { FragU f; f.q = x; return f.v; }

__device__ __forceinline__ u16 f2bf(float x) {
  __hip_bfloat16 h = __float2bfloat16(x);
  u16 r; __builtin_memcpy(&r, &h, 2); return r;
}

__device__ __forceinline__ u32 pk_bf16(float a, float b) {
  __hip_bfloat162 h = __float22bfloat162_rn(make_float2(a, b));
  u32 r; __builtin_memcpy(&r, &h, 4); return r;
}

__device__ __forceinline__ float fast_tanh(float x) {
  // tanh(x) = 1 - 2/(1 + exp2(x * 2*log2(e)))
  float t = __builtin_amdgcn_exp2f(x * 2.885390081777927f);
  return __builtin_fmaf(-2.0f, __builtin_amdgcn_rcpf(1.0f + t), 1.0f);
}

// Flipped orientation: every layer computes D[hidden][point] with A = W^T, B = activations.
// With contraction order K(ks,8q+j) = 32ks + 16*(j>>2) + 4q + (j&3), the next layer's
// B-fragment is exactly the lane's OWN packed tanh outputs of D-tiles 2ks, 2ks+1:
// activations never leave registers (no LDS hbuf, no shuffles, no repacks).
//
// HISTORY (rounds 1-7, measured on this toolchain):
//  - LLVM scheduler hoists unrolled ds_read chains en masse -> 0.5 GB scratch spill;
//    fixed by per-t-iteration sched_barrier (FETCH 513 MB -> 4.7 MB).
//  - Two-tile u/v + fences: 86 us, VGPR 52, VALUBusy 59%. Fence-mask relaxation (0x0F
//    vs 0): NO change -> the idle 40% is unhidden latency, and the cure is TLP.
//  - Occupancy was LDS-capped at 16 waves/CU (69 KB x 2 WGs of 512 thr). VGPR=52 <= 64
//    means 8 waves/SIMD is allocatable. THIS ROUND: 1024-thread WGs (16 waves) halve
//    LDS/wave: 2 x 1024-thr WGs/CU = 32 waves/CU, 8/SIMD, double TLP. VGPR cap 64 >= 52.
//    FETCH_SIZE is the spill tell (~4.7 MB = pass).

#define LDS_W2 0          // 32768 B
#define LDS_W3 32768      // 32768 B
#define LDS_W4 65536      //   512 B (2 rows x 256)
#define LDS_B2 66048      //   512 B f32[128]
#define LDS_B3 66560      //   512 B f32[128]
#define LDS_W1 67072      //  2048 B (128 rows x 16 B, q==0 A-chunk incl. bias at j=4)
#define LDS_TOTAL 69120   // 2 WGs/CU co-resident (138240 <= 163840)

__global__ void __launch_bounds__(1024, 2) mlp_fused(
    const float* __restrict__ Xg, const float* __restrict__ Yg,
    const float* __restrict__ C1g, const float* __restrict__ C2g,
    const float* __restrict__ W1g, const float* __restrict__ B1g,
    const float* __restrict__ W2g, const float* __restrict__ B2g,
    const float* __restrict__ W3g, const float* __restrict__ B3g,
    const float* __restrict__ W4g, const float* __restrict__ B4g,
    float* __restrict__ Og, int npts, int nwaves_total)
{
  extern __shared__ char lds[];
  const int tid = threadIdx.x;

  // ---- stage W2^T / W3^T as K-interleaved, bank-swizzled A-fragments ----
  for (int i = tid; i < 16384; i += 1024) {
    int k = i >> 7, n = i & 127;                       // W[k][n], k = hid_in, n = hid_out
    int kc = ((k >> 5) << 2) | ((k >> 2) & 3);         // chunk = 4*ks + q
    int j  = (k & 3) | (((k >> 4) & 1) << 2);          // slot within chunk
    int off = n * 256 + ((kc ^ (n & 15)) << 4) + (j << 1);
    *(u16*)(lds + LDS_W2 + off) = f2bf(W2g[i]);
    *(u16*)(lds + LDS_W3 + off) = f2bf(W3g[i]);
  }
  if (tid < 256) {                                     // W4 is [128][2] row-major
    int k = tid >> 1, o = tid & 1;
    int kc = ((k >> 5) << 2) | ((k >> 2) & 3);
    int j  = (k & 3) | (((k >> 4) & 1) << 2);
    *(u16*)(lds + LDS_W4 + o * 256 + (kc << 4) + (j << 1)) = f2bf(W4g[tid]);
  }
  if (tid < 128) {
    ((float*)(lds + LDS_B2))[tid] = B2g[tid];
    ((float*)(lds + LDS_B3))[tid] = B3g[tid];
    // W1 augmented A-chunk (q==0 only): j=0..3 -> W1[0..3][n], j=4 -> b1[n]
    u32* w1r = (u32*)(lds + LDS_W1 + tid * 16);
    w1r[0] = pk_bf16(W1g[tid],       W1g[128 + tid]);
    w1r[1] = pk_bf16(W1g[256 + tid], W1g[384 + tid]);
    w1r[2] = pk_bf16(B1g[tid], 0.f);
    w1r[3] = 0u;
  }
  __syncthreads();

  const int wave = tid >> 6;                 // 0..15
  const int lane = tid & 63;
  const int q = lane >> 4;
  const int c = lane & 15;
  const int wgid = blockIdx.x * 16 + wave;

  int posA[4];
#pragma unroll
  for (int ks = 0; ks < 4; ks++) posA[ks] = c * 256 + (((ks * 4 + q) ^ c) << 4);
  const int biasaddr = q * 16;
  const int w4addr = (c & 1) * 256 + q * 16;   // c>=2 lanes duplicate rows -> unused D rows
  const float b4_0 = B4g[0], b4_1 = B4g[1];

  const int nbatch = npts >> 5;   // 32 points (2 tiles of 16) per wave-iteration

  // software-pipelined input fetch (q==0 lanes only): raw floats stay live across
  // layers 2-4; packed to bf16 at the TOP of their own iteration so the vmcnt wait
  // lands ~3 layers after issue.
  float fxu = 0.f, fyu = 0.f, f1u = 0.f, f2u = 0.f;
  float fxv = 0.f, fyv = 0.f, f1v = 0.f, f2v = 0.f;
  const u32 b1w2 = (q == 0) ? 0x00003f80u : 0u;   // k=4 slot = 1.0 (bias row)
  if (wgid < nbatch && q == 0) {
    int iu = (wgid << 5) + c, iv = iu + 16;
    fxu = Xg[iu]; fyu = Yg[iu]; f1u = C1g[iu]; f2u = C2g[iu];
    fxv = Xg[iv]; fyv = Yg[iv]; f1v = C1g[iv]; f2v = C2g[iv];
  }

#pragma clang loop unroll(disable)
  for (int b = wgid; b < nbatch; b += nwaves_total) {
    // ---- layer 1 (K=5 augmented; bias folded into A row 4) ----
    const u32 b1u0 = pk_bf16(fxu, fyu), b1u1 = pk_bf16(f1u, f2u);
    const u32 b1v0 = pk_bf16(fxv, fyv), b1v1 = pk_bf16(f1v, f2v);
    u32 pu[16], pv[16];
#pragma unroll
    for (int t = 0; t < 8; t++) {
      u32x4 wf = {0u, 0u, 0u, 0u};
      if (q == 0) wf = *(const u32x4*)(lds + LDS_W1 + t * 256 + c * 16);
      f32x4 z = {0.f, 0.f, 0.f, 0.f};
      f32x4 acu = MFMA16(as_frag(wf), mk_frag(b1u0, b1u1, b1w2, 0u), z);
      f32x4 acv = MFMA16(as_frag(wf), mk_frag(b1v0, b1v1, b1w2, 0u), z);
      pu[2*t]   = pk_bf16(fast_tanh(acu[0]), fast_tanh(acu[1]));
      pu[2*t+1] = pk_bf16(fast_tanh(acu[2]), fast_tanh(acu[3]));
      pv[2*t]   = pk_bf16(fast_tanh(acv[0]), fast_tanh(acv[1]));
      pv[2*t+1] = pk_bf16(fast_tanh(acv[2]), fast_tanh(acv[3]));
      SBARM();   // fence: ds_reads pinned to their region; VALU/MFMA may interleave
    }

    // prefetch next iteration's inputs; vmcnt wait deferred to next iteration's top
    {
      int bn = b + nwaves_total;
      if (bn < nbatch && q == 0) {
        int iu = (bn << 5) + c, iv = iu + 16;
        fxu = Xg[iu]; fyu = Yg[iu]; f1u = C1g[iu]; f2u = C2g[iu];
        fxv = Xg[iv]; fyv = Yg[iv]; f1v = C1g[iv]; f2v = C2g[iv];
      }
    }
    SBARM();

    // ---- layer 2: registers -> registers (each weight frag feeds BOTH tiles) ----
    u32 qu[16], qv[16];
#pragma unroll
    for (int t = 0; t < 8; t++) {
      f32x4 bi = *(const f32x4*)(lds + LDS_B2 + t * 64 + biasaddr);
      f32x4 acu = bi, acv = bi;
#pragma unroll
      for (int ks = 0; ks < 4; ks++) {
        bf16x8 aw = *(const bf16x8*)(lds + LDS_W2 + t * 4096 + posA[ks]);
        acu = MFMA16(aw, mk_frag(pu[4*ks], pu[4*ks+1], pu[4*ks+2], pu[4*ks+3]), acu);
        acv = MFMA16(aw, mk_frag(pv[4*ks], pv[4*ks+1], pv[4*ks+2], pv[4*ks+3]), acv);
      }
      qu[2*t]   = pk_bf16(fast_tanh(acu[0]), fast_tanh(acu[1]));
      qu[2*t+1] = pk_bf16(fast_tanh(acu[2]), fast_tanh(acu[3]));
      qv[2*t]   = pk_bf16(fast_tanh(acv[0]), fast_tanh(acv[1]));
      qv[2*t+1] = pk_bf16(fast_tanh(acv[2]), fast_tanh(acv[3]));
      SBARM();   // fence: bounds in-flight weight fragments to one t-iteration
    }

    // ---- layer 3 fused with layer 4: L3's tile-pair output feeds L4's ks-MFMA
    // immediately, so it never lives as a full 32-word array ----
    f32x4 acu4 = {b4_0, b4_1, 0.f, 0.f};
    f32x4 acv4 = acu4;
#pragma unroll
    for (int tp = 0; tp < 4; tp++) {
      u32 pwu[4], pwv[4];
#pragma unroll
      for (int h = 0; h < 2; h++) {
        int t = tp * 2 + h;
        f32x4 bi = *(const f32x4*)(lds + LDS_B3 + t * 64 + biasaddr);
        f32x4 acu = bi, acv = bi;
#pragma unroll
        for (int ks = 0; ks < 4; ks++) {
          bf16x8 aw = *(const bf16x8*)(lds + LDS_W3 + t * 4096 + posA[ks]);
          acu = MFMA16(aw, mk_frag(qu[4*ks], qu[4*ks+1], qu[4*ks+2], qu[4*ks+3]), acu);
          acv = MFMA16(aw, mk_frag(qv[4*ks], qv[4*ks+1], qv[4*ks+2], qv[4*ks+3]), acv);
        }
        pwu[2*h]   = pk_bf16(fast_tanh(acu[0]), fast_tanh(acu[1]));
        pwu[2*h+1] = pk_bf16(fast_tanh(acu[2]), fast_tanh(acu[3]));
        pwv[2*h]   = pk_bf16(fast_tanh(acv[0]), fast_tanh(acv[1]));
        pwv[2*h+1] = pk_bf16(fast_tanh(acv[2]), fast_tanh(acv[3]));
        SBARM();
      }
      bf16x8 aw4 = *(const bf16x8*)(lds + LDS_W4 + w4addr + tp * 64);
      acu4 = MFMA16(aw4, mk_frag(pwu[0], pwu[1], pwu[2], pwu[3]), acu4);
      acv4 = MFMA16(aw4, mk_frag(pwv[0], pwv[1], pwv[2], pwv[3]), acv4);
      SBARM();
    }

    // ---- store (rows 0/1 of the padded N=16 tile are the two logits) ----
    if (q == 0) {
      const int pb = b << 5;
      f32x2 ou = {acu4[0], acu4[1]}, ov = {acv4[0], acv4[1]};
      *(f32x2*)(Og + (size_t)(pb + c) * 2)      = ou;
      *(f32x2*)(Og + (size_t)(pb + 16 + c) * 2) = ov;
    }
  }
}

extern "C" void kernel_launch(void* const* d_in, const int* in_sizes, int n_in,
                              void* d_out, int out_size, void* d_ws, size_t ws_size,
                              hipStream_t stream)
{
  (void)n_in; (void)out_size; (void)d_ws; (void)ws_size;
  const float* X  = (const float*)d_in[0];
  const float* Y  = (const float*)d_in[1];
  const float* C1 = (const float*)d_in[2];
  const float* C2 = (const float*)d_in[3];
  const float* W1 = (const float*)d_in[4];
  const float* B1 = (const float*)d_in[5];
  const float* W2 = (const float*)d_in[6];
  const float* B2 = (const float*)d_in[7];
  const float* W3 = (const float*)d_in[8];
  const float* B3 = (const float*)d_in[9];
  const float* W4 = (const float*)d_in[10];
  const float* B4 = (const float*)d_in[11];
  int npts = in_sizes[0];
  const int nblk = 512;               // 1024-thr WGs: 2 WGs/CU (LDS), 32 waves/CU
  const int nwaves = nblk * 16;
  hipLaunchKernelGGL(mlp_fused, dim3(nblk), dim3(1024), LDS_TOTAL, stream,
                     X, Y, C1, C2, W1, B1, W2, B2, W3, B3, W4, B4,
                     (float*)d_out, npts, nwaves);
}

// Round 10
// 144.961 us; speedup vs baseline: 2.1456x; 1.0138x over previous
//
#include <hip/hip_runtime.h>
#include <hip/hip_bf16.h>

using u16 = unsigned short;
using u32 = unsigned int;

typedef __attribute__((ext_vector_type(8))) short bf16x8;
typedef __attribute__((ext_vector_type(4))) float f32x4;
typedef __attribute__((ext_vector_type(2))) float f32x2;
typedef __attribute__((ext_vector_type(4))) u32 u32x4;

#define MFMA16(a, b, c) __builtin_amdgcn_mfma_f32_16x16x32_bf16((a), (b), (c), 0, 0, 0)
// Selective fence: ALU|VALU|SALU|MFMA (0x0F) MAY cross; all DS/VMEM may NOT.
// Blocks the mass ds_read hoisting that caused 0.5 GB scratch spill (rounds 2-4).
#define SBARM() __builtin_amdgcn_sched_barrier(0x0F)

union FragU { u32 u[4]; bf16x8 v; u32x4 q; };

__device__ __forceinline__ bf16x8 mk_frag(u32 a, u32 b, u32 c, u32 d) {
  FragU f; f.u[0] = a; f.u[1] = b; f.u[2] = c; f.u[3] = d; return f.v;
}
__device__ __forceinline__ bf16x8 as_frag(u32x4 x) { FragU f; f.q = x; return f.v; }

__device__ __forceinline__ u16 f2bf(float x) {
  __hip_bfloat16 h = __float2bfloat16(x);
  u16 r; __builtin_memcpy(&r, &h, 2); return r;
}

__device__ __forceinline__ u32 pk_bf16(float a, float b) {
  __hip_bfloat162 h = __float22bfloat162_rn(make_float2(a, b));
  u32 r; __builtin_memcpy(&r, &h, 4); return r;
}

#define TANH_C 2.885390081777927f   // 2*log2(e)

// tanh on a quad of pre-activations -> two packed bf16 words.
// Vector f32x2 C arithmetic: per-element IEEE ops BIT-IDENTICAL to the scalar
// fast_tanh path (fp-contract fuses r*N2+ONE into the same fma as __builtin_fmaf).
// NO inline asm (round-9 hand-written v_pk_* asm caused inf/NaN — root cause
// unresolved; compiler-selected packed ops are the safe route, cf. catalog m240).
__device__ __forceinline__ void tanh_quad(f32x4 z, u32& w0, u32& w1) {
  const f32x2 C2  = {TANH_C, TANH_C};
  const f32x2 ONE = {1.f, 1.f};
  const f32x2 N2  = {-2.f, -2.f};
  f32x2 z01 = {z[0], z[1]}, z23 = {z[2], z[3]};
  f32x2 s01 = z01 * C2, s23 = z23 * C2;
  f32x2 t01, t23;
  t01.x = __builtin_amdgcn_exp2f(s01.x); t01.y = __builtin_amdgcn_exp2f(s01.y);
  t23.x = __builtin_amdgcn_exp2f(s23.x); t23.y = __builtin_amdgcn_exp2f(s23.y);
  f32x2 a01 = t01 + ONE, a23 = t23 + ONE;
  f32x2 r01, r23;
  r01.x = __builtin_amdgcn_rcpf(a01.x); r01.y = __builtin_amdgcn_rcpf(a01.y);
  r23.x = __builtin_amdgcn_rcpf(a23.x); r23.y = __builtin_amdgcn_rcpf(a23.y);
  f32x2 h01 = r01 * N2 + ONE, h23 = r23 * N2 + ONE;
  w0 = pk_bf16(h01.x, h01.y);
  w1 = pk_bf16(h23.x, h23.y);
}

// Flipped orientation: every layer computes D[hidden][point] with A = W^T, B = activations.
// With contraction order K(ks,8q+j) = 32ks + 16*(j>>2) + 4q + (j&3), the next layer's
// B-fragment is exactly the lane's OWN packed tanh outputs: activations never leave
// registers (no LDS hbuf, no shuffles, no repacks).
//
// HISTORY (rounds 1-9, measured):
//  - LLVM hoists unrolled ds_read chains en masse -> 0.5 GB scratch spill; fixed by
//    per-t-iteration sched_barrier (FETCH 513 MB -> 4.7 MB).
//  - Two-tile u/v + fences: 86 us; 1024-thr WGs (32 waves/CU): 81 us, VGPR 60,
//    VALUBusy 66% -> VALU-issue-bound on the tanh stream.
//  - Round 9: hand-written v_pk_* inline asm + branchless W1 + all-lane bias slot
//    -> absmax inf (FAILED, root cause unresolved; asm is prime suspect). This round:
//    exact round-8 structure, tanh tail as vector-C (compiler-selected packing only).

#define LDS_W2 0          // 32768 B
#define LDS_W3 32768      // 32768 B
#define LDS_W4 65536      //   512 B (2 rows x 256)
#define LDS_B2 66048      //   512 B f32[128]
#define LDS_B3 66560      //   512 B f32[128]
#define LDS_W1 67072      //  2048 B (128 rows x 16 B, q==0 A-chunk incl. bias at j=4)
#define LDS_TOTAL 69120   // 2 WGs/CU co-resident (138240 <= 163840)

__global__ void __launch_bounds__(1024, 2) mlp_fused(
    const float* __restrict__ Xg, const float* __restrict__ Yg,
    const float* __restrict__ C1g, const float* __restrict__ C2g,
    const float* __restrict__ W1g, const float* __restrict__ B1g,
    const float* __restrict__ W2g, const float* __restrict__ B2g,
    const float* __restrict__ W3g, const float* __restrict__ B3g,
    const float* __restrict__ W4g, const float* __restrict__ B4g,
    float* __restrict__ Og, int npts, int nwaves_total)
{
  extern __shared__ char lds[];
  const int tid = threadIdx.x;

  // ---- stage W2^T / W3^T as K-interleaved, bank-swizzled A-fragments ----
  for (int i = tid; i < 16384; i += 1024) {
    int k = i >> 7, n = i & 127;                       // W[k][n], k = hid_in, n = hid_out
    int kc = ((k >> 5) << 2) | ((k >> 2) & 3);         // chunk = 4*ks + q
    int j  = (k & 3) | (((k >> 4) & 1) << 2);          // slot within chunk
    int off = n * 256 + ((kc ^ (n & 15)) << 4) + (j << 1);
    *(u16*)(lds + LDS_W2 + off) = f2bf(W2g[i]);
    *(u16*)(lds + LDS_W3 + off) = f2bf(W3g[i]);
  }
  if (tid < 256) {                                     // W4 is [128][2] row-major
    int k = tid >> 1, o = tid & 1;
    int kc = ((k >> 5) << 2) | ((k >> 2) & 3);
    int j  = (k & 3) | (((k >> 4) & 1) << 2);
    *(u16*)(lds + LDS_W4 + o * 256 + (kc << 4) + (j << 1)) = f2bf(W4g[tid]);
  }
  if (tid < 128) {
    ((float*)(lds + LDS_B2))[tid] = B2g[tid];
    ((float*)(lds + LDS_B3))[tid] = B3g[tid];
    // W1 augmented A-chunk (q==0 only): j=0..3 -> W1[0..3][n], j=4 -> b1[n]
    u32* w1r = (u32*)(lds + LDS_W1 + tid * 16);
    w1r[0] = pk_bf16(W1g[tid],       W1g[128 + tid]);
    w1r[1] = pk_bf16(W1g[256 + tid], W1g[384 + tid]);
    w1r[2] = pk_bf16(B1g[tid], 0.f);
    w1r[3] = 0u;
  }
  __syncthreads();

  const int wave = tid >> 6;                 // 0..15
  const int lane = tid & 63;
  const int q = lane >> 4;
  const int c = lane & 15;
  const int wgid = blockIdx.x * 16 + wave;

  int posA[4];
#pragma unroll
  for (int ks = 0; ks < 4; ks++) posA[ks] = c * 256 + (((ks * 4 + q) ^ c) << 4);
  const int biasaddr = q * 16;
  const int w4addr = (c & 1) * 256 + q * 16;   // c>=2 lanes duplicate rows -> unused D rows
  const float b4_0 = B4g[0], b4_1 = B4g[1];

  const int nbatch = npts >> 5;   // 32 points (2 tiles of 16) per wave-iteration

  // software-pipelined input fetch (q==0 lanes only): raw floats stay live across
  // layers 2-4; packed to bf16 at the TOP of their own iteration.
  float fxu = 0.f, fyu = 0.f, f1u = 0.f, f2u = 0.f;
  float fxv = 0.f, fyv = 0.f, f1v = 0.f, f2v = 0.f;
  const u32 b1w2 = (q == 0) ? 0x00003f80u : 0u;   // k=4 slot = 1.0 (bias row)
  if (wgid < nbatch && q == 0) {
    int iu = (wgid << 5) + c, iv = iu + 16;
    fxu = Xg[iu]; fyu = Yg[iu]; f1u = C1g[iu]; f2u = C2g[iu];
    fxv = Xg[iv]; fyv = Yg[iv]; f1v = C1g[iv]; f2v = C2g[iv];
  }

#pragma clang loop unroll(disable)
  for (int b = wgid; b < nbatch; b += nwaves_total) {
    // ---- layer 1 (K=5 augmented; bias folded into A row 4) ----
    const u32 b1u0 = pk_bf16(fxu, fyu), b1u1 = pk_bf16(f1u, f2u);
    const u32 b1v0 = pk_bf16(fxv, fyv), b1v1 = pk_bf16(f1v, f2v);
    u32 pu[16], pv[16];
#pragma unroll
    for (int t = 0; t < 8; t++) {
      u32x4 wf = {0u, 0u, 0u, 0u};
      if (q == 0) wf = *(const u32x4*)(lds + LDS_W1 + t * 256 + c * 16);
      f32x4 z = {0.f, 0.f, 0.f, 0.f};
      f32x4 acu = MFMA16(as_frag(wf), mk_frag(b1u0, b1u1, b1w2, 0u), z);
      f32x4 acv = MFMA16(as_frag(wf), mk_frag(b1v0, b1v1, b1w2, 0u), z);
      tanh_quad(acu, pu[2*t], pu[2*t+1]);
      tanh_quad(acv, pv[2*t], pv[2*t+1]);
      SBARM();   // fence: ds_reads pinned to their region; VALU/MFMA may interleave
    }

    // prefetch next iteration's inputs; vmcnt wait deferred to next iteration's top
    {
      int bn = b + nwaves_total;
      if (bn < nbatch && q == 0) {
        int iu = (bn << 5) + c, iv = iu + 16;
        fxu = Xg[iu]; fyu = Yg[iu]; f1u = C1g[iu]; f2u = C2g[iu];
        fxv = Xg[iv]; fyv = Yg[iv]; f1v = C1g[iv]; f2v = C2g[iv];
      }
    }
    SBARM();

    // ---- layer 2: registers -> registers (each weight frag feeds BOTH tiles) ----
    u32 qu[16], qv[16];
#pragma unroll
    for (int t = 0; t < 8; t++) {
      f32x4 bi = *(const f32x4*)(lds + LDS_B2 + t * 64 + biasaddr);
      f32x4 acu = bi, acv = bi;
#pragma unroll
      for (int ks = 0; ks < 4; ks++) {
        bf16x8 aw = *(const bf16x8*)(lds + LDS_W2 + t * 4096 + posA[ks]);
        acu = MFMA16(aw, mk_frag(pu[4*ks], pu[4*ks+1], pu[4*ks+2], pu[4*ks+3]), acu);
        acv = MFMA16(aw, mk_frag(pv[4*ks], pv[4*ks+1], pv[4*ks+2], pv[4*ks+3]), acv);
      }
      tanh_quad(acu, qu[2*t], qu[2*t+1]);
      tanh_quad(acv, qv[2*t], qv[2*t+1]);
      SBARM();   // fence: bounds in-flight weight fragments to one t-iteration
    }

    // ---- layer 3 fused with layer 4: L3's tile-pair output feeds L4's ks-MFMA
    // immediately, so it never lives as a full 32-word array ----
    f32x4 acu4 = {b4_0, b4_1, 0.f, 0.f};
    f32x4 acv4 = acu4;
#pragma unroll
    for (int tp = 0; tp < 4; tp++) {
      u32 pwu[4], pwv[4];
#pragma unroll
      for (int h = 0; h < 2; h++) {
        int t = tp * 2 + h;
        f32x4 bi = *(const f32x4*)(lds + LDS_B3 + t * 64 + biasaddr);
        f32x4 acu = bi, acv = bi;
#pragma unroll
        for (int ks = 0; ks < 4; ks++) {
          bf16x8 aw = *(const bf16x8*)(lds + LDS_W3 + t * 4096 + posA[ks]);
          acu = MFMA16(aw, mk_frag(qu[4*ks], qu[4*ks+1], qu[4*ks+2], qu[4*ks+3]), acu);
          acv = MFMA16(aw, mk_frag(qv[4*ks], qv[4*ks+1], qv[4*ks+2], qv[4*ks+3]), acv);
        }
        tanh_quad(acu, pwu[2*h], pwu[2*h+1]);
        tanh_quad(acv, pwv[2*h], pwv[2*h+1]);
        SBARM();
      }
      bf16x8 aw4 = *(const bf16x8*)(lds + LDS_W4 + w4addr + tp * 64);
      acu4 = MFMA16(aw4, mk_frag(pwu[0], pwu[1], pwu[2], pwu[3]), acu4);
      acv4 = MFMA16(aw4, mk_frag(pwv[0], pwv[1], pwv[2], pwv[3]), acv4);
      SBARM();
    }

    // ---- store (rows 0/1 of the padded N=16 tile are the two logits) ----
    if (q == 0) {
      const int pb = b << 5;
      f32x2 ou = {acu4[0], acu4[1]}, ov = {acv4[0], acv4[1]};
      *(f32x2*)(Og + (size_t)(pb + c) * 2)      = ou;
      *(f32x2*)(Og + (size_t)(pb + 16 + c) * 2) = ov;
    }
  }
}

extern "C" void kernel_launch(void* const* d_in, const int* in_sizes, int n_in,
                              void* d_out, int out_size, void* d_ws, size_t ws_size,
                              hipStream_t stream)
{
  (void)n_in; (void)out_size; (void)d_ws; (void)ws_size;
  const float* X  = (const float*)d_in[0];
  const float* Y  = (const float*)d_in[1];
  const float* C1 = (const float*)d_in[2];
  const float* C2 = (const float*)d_in[3];
  const float* W1 = (const float*)d_in[4];
  const float* B1 = (const float*)d_in[5];
  const float* W2 = (const float*)d_in[6];
  const float* B2 = (const float*)d_in[7];
  const float* W3 = (const float*)d_in[8];
  const float* B3 = (const float*)d_in[9];
  const float* W4 = (const float*)d_in[10];
  const float* B4 = (const float*)d_in[11];
  int npts = in_sizes[0];
  const int nblk = 512;               // 1024-thr WGs: 2 WGs/CU (LDS 69120 B each)
  const int nwaves = nblk * 16;
  hipLaunchKernelGGL(mlp_fused, dim3(nblk), dim3(1024), LDS_TOTAL, stream,
                     X, Y, C1, C2, W1, B1, W2, B2, W3, B3, W4, B4,
                     (float*)d_out, npts, nwaves);
}

// Round 11
// 137.022 us; speedup vs baseline: 2.2699x; 1.0579x over previous
//
#include <hip/hip_runtime.h>
#include <hip/hip_bf16.h>
#include <math.h>

using u16 = unsigned short;
using u32 = unsigned int;

typedef __attribute__((ext_vector_type(8))) short bf16x8;
typedef __attribute__((ext_vector_type(4))) float f32x4;
typedef __attribute__((ext_vector_type(2))) float f32x2;
typedef __attribute__((ext_vector_type(4))) u32 u32x4;

#define MFMA16(a, b, c) __builtin_amdgcn_mfma_f32_16x16x32_bf16((a), (b), (c), 0, 0, 0)
// Selective fence: ALU|VALU|SALU|MFMA (0x0F) MAY cross; all DS/VMEM may NOT.
// Blocks the mass ds_read hoisting that caused 0.5 GB scratch spill (rounds 2-4).
#define SBARM() __builtin_amdgcn_sched_barrier(0x0F)

union FragU { u32 u[4]; bf16x8 v; u32x4 q; };

__device__ __forceinline__ bf16x8 mk_frag(u32 a, u32 b, u32 c, u32 d) {
  FragU f; f.u[0] = a; f.u[1] = b; f.u[2] = c; f.u[3] = d; return f.v;
}
__device__ __forceinline__ bf16x8 as_frag(u32x4 x) { FragU f; f.q = x; return f.v; }

__device__ __forceinline__ u16 f2bf(float x) {
  __hip_bfloat16 h = __float2bfloat16(x);
  u16 r; __builtin_memcpy(&r, &h, 2); return r;
}

__device__ __forceinline__ u32 pk_bf16(float a, float b) {
  __hip_bfloat162 h = __float22bfloat162_rn(make_float2(a, b));
  u32 r; __builtin_memcpy(&r, &h, 4); return r;
}

// HISTORY (rounds 1-10, measured on this toolchain):
//  - LLVM hoists unrolled ds_read chains en masse -> 0.5 GB scratch spill; fixed by
//    per-t-iteration sched_barrier (FETCH 513 MB -> 4.7 MB).
//  - Two-tile u/v + fences + 1024-thr WGs: 81 us, VGPR 60, VALUBusy ~62%.
//  - Round 10 (packed-VALU tanh tail): NEUTRAL, counters identical -> the VALU time is
//    dominated by 384 trans instrs/iter (exp2+rcp at 1/4 rate ~ 3072 of ~5350 cyc).
//  - THIS ROUND: kill the trans pipe entirely -> tanh via 4096-entry bf16 LDS LUT over
//    [-4,4) (bin 1/512, midpoint; cvt_u32 saturates negatives, min clamps high; tanh
//    saturates to +-0.99933 at the edges, err <= 0.0007). LUT quantization error
//    <= 0.001 + bf16 rounding ~ below the existing bf16 activation rounding.
//    Layer 4 (logits, no activation) untouched. 8 KB extra LDS: 2 WGs/CU still fit.

__device__ __forceinline__ void lut_quad(const char* lut, f32x4 z, u32& w0, u32& w1) {
  float f0 = __builtin_fmaf(z[0], 512.f, 2048.f);
  float f1 = __builtin_fmaf(z[1], 512.f, 2048.f);
  float f2 = __builtin_fmaf(z[2], 512.f, 2048.f);
  float f3 = __builtin_fmaf(z[3], 512.f, 2048.f);
  u32 i0 = (u32)f0, i1 = (u32)f1, i2 = (u32)f2, i3 = (u32)f3;  // v_cvt_u32: neg -> 0
  i0 = i0 > 4095u ? 4095u : i0;
  i1 = i1 > 4095u ? 4095u : i1;
  i2 = i2 > 4095u ? 4095u : i2;
  i3 = i3 > 4095u ? 4095u : i3;
  u32 t0 = *(const u16*)(lut + i0 * 2);
  u32 t1 = *(const u16*)(lut + i1 * 2);
  u32 t2 = *(const u16*)(lut + i2 * 2);
  u32 t3 = *(const u16*)(lut + i3 * 2);
  w0 = t0 | (t1 << 16);   // v_lshl_or_b32
  w1 = t2 | (t3 << 16);
}

#define LDS_W2 0          // 32768 B
#define LDS_W3 32768      // 32768 B
#define LDS_W4 65536      //   512 B (2 rows x 256)
#define LDS_B2 66048      //   512 B f32[128]
#define LDS_B3 66560      //   512 B f32[128]
#define LDS_W1 67072      //  2048 B (128 rows x 16 B, q==0 A-chunk incl. bias at j=4)
#define LDS_LUT 69120     //  8192 B (4096 x u16 bf16 tanh table)
#define LDS_TOTAL 77312   // 2 WGs/CU co-resident (154624 <= 163840)

__global__ void __launch_bounds__(1024, 2) mlp_fused(
    const float* __restrict__ Xg, const float* __restrict__ Yg,
    const float* __restrict__ C1g, const float* __restrict__ C2g,
    const float* __restrict__ W1g, const float* __restrict__ B1g,
    const float* __restrict__ W2g, const float* __restrict__ B2g,
    const float* __restrict__ W3g, const float* __restrict__ B3g,
    const float* __restrict__ W4g, const float* __restrict__ B4g,
    float* __restrict__ Og, int npts, int nwaves_total)
{
  extern __shared__ char lds[];
  const int tid = threadIdx.x;

  // ---- stage W2^T / W3^T as K-interleaved, bank-swizzled A-fragments ----
  for (int i = tid; i < 16384; i += 1024) {
    int k = i >> 7, n = i & 127;                       // W[k][n], k = hid_in, n = hid_out
    int kc = ((k >> 5) << 2) | ((k >> 2) & 3);         // chunk = 4*ks + q
    int j  = (k & 3) | (((k >> 4) & 1) << 2);          // slot within chunk
    int off = n * 256 + ((kc ^ (n & 15)) << 4) + (j << 1);
    *(u16*)(lds + LDS_W2 + off) = f2bf(W2g[i]);
    *(u16*)(lds + LDS_W3 + off) = f2bf(W3g[i]);
  }
  // ---- tanh LUT: 4096 midpoint samples of [-4,4), bf16 ----
  for (int i = tid; i < 4096; i += 1024) {
    float zc = (float)i * (1.0f / 512.0f) + (0.5f / 512.0f - 4.0f);
    *(u16*)(lds + LDS_LUT + i * 2) = f2bf(tanhf(zc));
  }
  if (tid < 256) {                                     // W4 is [128][2] row-major
    int k = tid >> 1, o = tid & 1;
    int kc = ((k >> 5) << 2) | ((k >> 2) & 3);
    int j  = (k & 3) | (((k >> 4) & 1) << 2);
    *(u16*)(lds + LDS_W4 + o * 256 + (kc << 4) + (j << 1)) = f2bf(W4g[tid]);
  }
  if (tid < 128) {
    ((float*)(lds + LDS_B2))[tid] = B2g[tid];
    ((float*)(lds + LDS_B3))[tid] = B3g[tid];
    // W1 augmented A-chunk (q==0 only): j=0..3 -> W1[0..3][n], j=4 -> b1[n]
    u32* w1r = (u32*)(lds + LDS_W1 + tid * 16);
    w1r[0] = pk_bf16(W1g[tid],       W1g[128 + tid]);
    w1r[1] = pk_bf16(W1g[256 + tid], W1g[384 + tid]);
    w1r[2] = pk_bf16(B1g[tid], 0.f);
    w1r[3] = 0u;
  }
  __syncthreads();

  const int wave = tid >> 6;                 // 0..15
  const int lane = tid & 63;
  const int q = lane >> 4;
  const int c = lane & 15;
  const int wgid = blockIdx.x * 16 + wave;
  const char* lut = lds + LDS_LUT;

  int posA[4];
#pragma unroll
  for (int ks = 0; ks < 4; ks++) posA[ks] = c * 256 + (((ks * 4 + q) ^ c) << 4);
  const int biasaddr = q * 16;
  const int w4addr = (c & 1) * 256 + q * 16;   // c>=2 lanes duplicate rows -> unused D rows
  const float b4_0 = B4g[0], b4_1 = B4g[1];

  const int nbatch = npts >> 5;   // 32 points (2 tiles of 16) per wave-iteration

  // software-pipelined input fetch (q==0 lanes only): raw floats stay live across
  // layers 2-4; packed to bf16 at the TOP of their own iteration.
  float fxu = 0.f, fyu = 0.f, f1u = 0.f, f2u = 0.f;
  float fxv = 0.f, fyv = 0.f, f1v = 0.f, f2v = 0.f;
  const u32 b1w2 = (q == 0) ? 0x00003f80u : 0u;   // k=4 slot = 1.0 (bias row)
  if (wgid < nbatch && q == 0) {
    int iu = (wgid << 5) + c, iv = iu + 16;
    fxu = Xg[iu]; fyu = Yg[iu]; f1u = C1g[iu]; f2u = C2g[iu];
    fxv = Xg[iv]; fyv = Yg[iv]; f1v = C1g[iv]; f2v = C2g[iv];
  }

#pragma clang loop unroll(disable)
  for (int b = wgid; b < nbatch; b += nwaves_total) {
    // ---- layer 1 (K=5 augmented; bias folded into A row 4) ----
    const u32 b1u0 = pk_bf16(fxu, fyu), b1u1 = pk_bf16(f1u, f2u);
    const u32 b1v0 = pk_bf16(fxv, fyv), b1v1 = pk_bf16(f1v, f2v);
    u32 pu[16], pv[16];
#pragma unroll
    for (int t = 0; t < 8; t++) {
      u32x4 wf = {0u, 0u, 0u, 0u};
      if (q == 0) wf = *(const u32x4*)(lds + LDS_W1 + t * 256 + c * 16);
      f32x4 z = {0.f, 0.f, 0.f, 0.f};
      f32x4 acu = MFMA16(as_frag(wf), mk_frag(b1u0, b1u1, b1w2, 0u), z);
      f32x4 acv = MFMA16(as_frag(wf), mk_frag(b1v0, b1v1, b1w2, 0u), z);
      lut_quad(lut, acu, pu[2*t], pu[2*t+1]);
      lut_quad(lut, acv, pv[2*t], pv[2*t+1]);
      SBARM();   // fence: ds ops pinned to their region; VALU/MFMA may interleave
    }

    // prefetch next iteration's inputs; vmcnt wait deferred to next iteration's top
    {
      int bn = b + nwaves_total;
      if (bn < nbatch && q == 0) {
        int iu = (bn << 5) + c, iv = iu + 16;
        fxu = Xg[iu]; fyu = Yg[iu]; f1u = C1g[iu]; f2u = C2g[iu];
        fxv = Xg[iv]; fyv = Yg[iv]; f1v = C1g[iv]; f2v = C2g[iv];
      }
    }
    SBARM();

    // ---- layer 2: registers -> registers (each weight frag feeds BOTH tiles) ----
    u32 qu[16], qv[16];
#pragma unroll
    for (int t = 0; t < 8; t++) {
      f32x4 bi = *(const f32x4*)(lds + LDS_B2 + t * 64 + biasaddr);
      f32x4 acu = bi, acv = bi;
#pragma unroll
      for (int ks = 0; ks < 4; ks++) {
        bf16x8 aw = *(const bf16x8*)(lds + LDS_W2 + t * 4096 + posA[ks]);
        acu = MFMA16(aw, mk_frag(pu[4*ks], pu[4*ks+1], pu[4*ks+2], pu[4*ks+3]), acu);
        acv = MFMA16(aw, mk_frag(pv[4*ks], pv[4*ks+1], pv[4*ks+2], pv[4*ks+3]), acv);
      }
      lut_quad(lut, acu, qu[2*t], qu[2*t+1]);
      lut_quad(lut, acv, qv[2*t], qv[2*t+1]);
      SBARM();   // fence: bounds in-flight ds ops to one t-iteration
    }

    // ---- layer 3 fused with layer 4: L3's tile-pair output feeds L4's ks-MFMA
    // immediately, so it never lives as a full 32-word array ----
    f32x4 acu4 = {b4_0, b4_1, 0.f, 0.f};
    f32x4 acv4 = acu4;
#pragma unroll
    for (int tp = 0; tp < 4; tp++) {
      u32 pwu[4], pwv[4];
#pragma unroll
      for (int h = 0; h < 2; h++) {
        int t = tp * 2 + h;
        f32x4 bi = *(const f32x4*)(lds + LDS_B3 + t * 64 + biasaddr);
        f32x4 acu = bi, acv = bi;
#pragma unroll
        for (int ks = 0; ks < 4; ks++) {
          bf16x8 aw = *(const bf16x8*)(lds + LDS_W3 + t * 4096 + posA[ks]);
          acu = MFMA16(aw, mk_frag(qu[4*ks], qu[4*ks+1], qu[4*ks+2], qu[4*ks+3]), acu);
          acv = MFMA16(aw, mk_frag(qv[4*ks], qv[4*ks+1], qv[4*ks+2], qv[4*ks+3]), acv);
        }
        lut_quad(lut, acu, pwu[2*h], pwu[2*h+1]);
        lut_quad(lut, acv, pwv[2*h], pwv[2*h+1]);
        SBARM();
      }
      bf16x8 aw4 = *(const bf16x8*)(lds + LDS_W4 + w4addr + tp * 64);
      acu4 = MFMA16(aw4, mk_frag(pwu[0], pwu[1], pwu[2], pwu[3]), acu4);
      acv4 = MFMA16(aw4, mk_frag(pwv[0], pwv[1], pwv[2], pwv[3]), acv4);
      SBARM();
    }

    // ---- store (rows 0/1 of the padded N=16 tile are the two logits) ----
    if (q == 0) {
      const int pb = b << 5;
      f32x2 ou = {acu4[0], acu4[1]}, ov = {acv4[0], acv4[1]};
      *(f32x2*)(Og + (size_t)(pb + c) * 2)      = ou;
      *(f32x2*)(Og + (size_t)(pb + 16 + c) * 2) = ov;
    }
  }
}

extern "C" void kernel_launch(void* const* d_in, const int* in_sizes, int n_in,
                              void* d_out, int out_size, void* d_ws, size_t ws_size,
                              hipStream_t stream)
{
  (void)n_in; (void)out_size; (void)d_ws; (void)ws_size;
  const float* X  = (const float*)d_in[0];
  const float* Y  = (const float*)d_in[1];
  const float* C1 = (const float*)d_in[2];
  const float* C2 = (const float*)d_in[3];
  const float* W1 = (const float*)d_in[4];
  const float* B1 = (const float*)d_in[5];
  const float* W2 = (const float*)d_in[6];
  const float* B2 = (const float*)d_in[7];
  const float* W3 = (const float*)d_in[8];
  const float* B3 = (const float*)d_in[9];
  const float* W4 = (const float*)d_in[10];
  const float* B4 = (const float*)d_in[11];
  int npts = in_sizes[0];
  const int nblk = 512;               // 1024-thr WGs: 2 WGs/CU (LDS 77312 B each)
  const int nwaves = nblk * 16;
  hipLaunchKernelGGL(mlp_fused, dim3(nblk), dim3(1024), LDS_TOTAL, stream,
                     X, Y, C1, C2, W1, B1, W2, B2, W3, B3, W4, B4,
                     (float*)d_out, npts, nwaves);
}